// Round 1
// baseline (1559.598 us; speedup 1.0000x reference)
//
#include <hip/hip_runtime.h>
#include <hip/hip_bf16.h>

#define N_NODES 500000
#define FEAT 256
#define NCLS 128
#define NSEG 2048

typedef __attribute__((ext_vector_type(8))) short bfrag8;   // 8 bf16 = 4 VGPRs
typedef __attribute__((ext_vector_type(4))) float facc4;    // 4 fp32 acc

__device__ __forceinline__ unsigned short f2bf(float f) {
    unsigned int u = __float_as_uint(f);
    u += 0x7FFFu + ((u >> 16) & 1u);   // round-to-nearest-even
    return (unsigned short)(u >> 16);
}

// K0: transpose + bf16-convert weights. W1t[f][d] = W1[d][f], W2t[c][d] = W2[d][c]
__global__ void prep_kernel(const float* __restrict__ W1, const float* __restrict__ W2,
                            short* __restrict__ W1t, short* __restrict__ W2t) {
    int idx = blockIdx.x * 256 + threadIdx.x;
    if (idx < FEAT * FEAT) {
        int d = idx >> 8, f = idx & 255;
        W1t[f * FEAT + d] = (short)f2bf(W1[idx]);
    }
    if (idx < FEAT * NCLS) {
        int d = idx >> 7, c = idx & 127;
        W2t[c * FEAT + d] = (short)f2bf(W2[idx]);
    }
}

// K0b: zero Lsum (2048*128 floats = 256 blocks * 256 threads * float4)
__global__ void zero_kernel(float4* __restrict__ p) {
    p[blockIdx.x * 256 + threadIdx.x] = (float4){0.f, 0.f, 0.f, 0.f};
}

// K1: fused MLP, barrier-free. 4 waves/block, each wave owns 16 rows.
// LDS halved vs v1 (32 KB/block -> 4 blocks/CU instead of 2) to fix the
// occupancy cap that left all pipes idle. A-row preloaded/converted up front
// so the 16 HBM dwordx4 loads are all in flight before the MFMA chain starts.
__global__ __launch_bounds__(256, 4)
void mlp_kernel(const float* __restrict__ H, const short* __restrict__ W1t,
                const float* __restrict__ b1, const short* __restrict__ W2t,
                const float* __restrict__ b2, float* __restrict__ logits) {
    __shared__ short hb[4][16 * 256];   // per-wave h buffer (8 KB), XOR-swizzled 8-elem groups

    const int tid  = threadIdx.x;
    const int lane = tid & 63;
    const int l15  = lane & 15;
    const int quad = lane >> 4;
    const int wave = tid >> 6;
    const int row0 = blockIdx.x * 64 + wave * 16;
    short* hw = hb[wave];

    // clamped row pointer (OOB rows compute garbage, never stored)
    const int rg = min(row0 + l15, N_NODES - 1);
    const float* rA = H + (size_t)rg * FEAT;

    // ---- preload + convert the whole A row strip (16 global dwordx4, issued early) ----
    bfrag8 af[8];
    #pragma unroll
    for (int kk = 0; kk < 8; ++kk) {
        const int kb = kk * 32 + quad * 8;          // lane's K base (8 elems)
        float4 lo = *reinterpret_cast<const float4*>(rA + kb);
        float4 hi = *reinterpret_cast<const float4*>(rA + kb + 4);
        bfrag8 a;
        a[0]=(short)f2bf(lo.x); a[1]=(short)f2bf(lo.y); a[2]=(short)f2bf(lo.z); a[3]=(short)f2bf(lo.w);
        a[4]=(short)f2bf(hi.x); a[5]=(short)f2bf(hi.y); a[6]=(short)f2bf(hi.z); a[7]=(short)f2bf(hi.w);
        af[kk] = a;
    }

    // ---- GEMM1: h = relu(A @ W1 + b1); acc 16 rows x 256 cols per wave ----
    facc4 acc[16];
    #pragma unroll
    for (int ct = 0; ct < 16; ++ct)
        acc[ct] = (facc4){0.f, 0.f, 0.f, 0.f};

    #pragma unroll
    for (int kk = 0; kk < 8; ++kk) {
        const int kb = kk * 32 + quad * 8;
        #pragma unroll
        for (int ct = 0; ct < 16; ++ct) {
            bfrag8 b = *reinterpret_cast<const bfrag8*>(&W1t[(ct * 16 + l15) * FEAT + kb]);
            acc[ct] = __builtin_amdgcn_mfma_f32_16x16x32_bf16(af[kk], b, acc[ct], 0, 0, 0);
        }
    }

    // ---- epilogue1: bias + relu -> per-wave LDS (swizzled), scalar b16 writes ----
    // C/D layout: col = ct*16 + l15, local row = quad*4 + i
    #pragma unroll
    for (int ct = 0; ct < 16; ++ct) {
        float bias = b1[ct * 16 + l15];
        int c = ct * 16 + l15;
        int rbase = quad * 4;
        #pragma unroll
        for (int i = 0; i < 4; ++i) {
            float v = fmaxf(acc[ct][i] + bias, 0.f);
            int r = rbase + i;
            int g = (c >> 3) ^ (r & 7);
            hw[r * 256 + g * 8 + (c & 7)] = (short)f2bf(v);
        }
    }

    // ---- GEMM2: logits = h @ W2 + b2 (A-frags from per-wave LDS) ----
    const int rx = l15 & 7;
    facc4 acc2[8];
    #pragma unroll
    for (int ct = 0; ct < 8; ++ct)
        acc2[ct] = (facc4){0.f, 0.f, 0.f, 0.f};

    #pragma unroll
    for (int kk = 0; kk < 8; ++kk) {
        const int kb = kk * 32 + quad * 8;
        const int gs = ((kb >> 3) ^ rx) << 3;
        bfrag8 a = *reinterpret_cast<const bfrag8*>(&hw[l15 * 256 + gs]);
        #pragma unroll
        for (int ct = 0; ct < 8; ++ct) {
            bfrag8 b = *reinterpret_cast<const bfrag8*>(&W2t[(ct * 16 + l15) * FEAT + kb]);
            acc2[ct] = __builtin_amdgcn_mfma_f32_16x16x32_bf16(a, b, acc2[ct], 0, 0, 0);
        }
    }

    // ---- epilogue2: bias + store logits (fp32, guarded) ----
    #pragma unroll
    for (int ct = 0; ct < 8; ++ct) {
        float bias = b2[ct * 16 + l15];
        int c = ct * 16 + l15;
        int rbase = row0 + quad * 4;
        #pragma unroll
        for (int i = 0; i < 4; ++i) {
            int r = rbase + i;
            if (r < N_NODES)
                logits[(size_t)r * NCLS + c] = acc2[ct][i] + bias;
        }
    }
}

// K2: per-segment sum of exp(logits). Balanced: blocks own 256 contiguous rows;
// each thread walks its stride-8 row slice (seg ids monotone since batch sorted),
// accumulates while seg unchanged, atomicAdd-flushes on transitions.
// No binary search, no per-segment load imbalance. ~2.3M float atomics total.
__global__ void seg_sum_kernel(const float* __restrict__ logits,
                               const int* __restrict__ batch,
                               float* __restrict__ Lsum) {
    int t = threadIdx.x;
    int cg = t & 31;          // col group (4 cols)
    int rs = t >> 5;          // row slice 0..7
    int r0 = blockIdx.x * 256;
    int rend = min(r0 + 256, N_NODES);

    float4 s = {0.f, 0.f, 0.f, 0.f};
    int cur = -1;
    for (int r = r0 + rs; r < rend; r += 8) {
        int seg = batch[r];
        float4 v = *reinterpret_cast<const float4*>(&logits[(size_t)r * NCLS + cg * 4]);
        if (seg != cur) {
            if (cur >= 0) {
                float* dst = &Lsum[(size_t)cur * NCLS + cg * 4];
                atomicAdd(dst + 0, s.x); atomicAdd(dst + 1, s.y);
                atomicAdd(dst + 2, s.z); atomicAdd(dst + 3, s.w);
            }
            cur = seg;
            s = (float4){0.f, 0.f, 0.f, 0.f};
        }
        s.x += __expf(v.x); s.y += __expf(v.y);
        s.z += __expf(v.z); s.w += __expf(v.w);
    }
    if (cur >= 0) {
        float* dst = &Lsum[(size_t)cur * NCLS + cg * 4];
        atomicAdd(dst + 0, s.x); atomicAdd(dst + 1, s.y);
        atomicAdd(dst + 2, s.z); atomicAdd(dst + 3, s.w);
    }
}

// K3: probs = exp(logit) / Lsum[seg][c]
__global__ void probs_kernel(const float* __restrict__ logits,
                             const int* __restrict__ batch,
                             const float* __restrict__ Lsum,
                             float* __restrict__ probs) {
    int idx = blockIdx.x * 256 + threadIdx.x;
    int n = idx >> 5;
    if (n >= N_NODES) return;
    int c4 = (idx & 31) << 2;
    int seg = batch[n];
    float4 lg = *reinterpret_cast<const float4*>(&logits[(size_t)n * NCLS + c4]);
    float4 L  = *reinterpret_cast<const float4*>(&Lsum[(size_t)seg * NCLS + c4]);
    float4 p;
    p.x = __expf(lg.x) / L.x; p.y = __expf(lg.y) / L.y;
    p.z = __expf(lg.z) / L.z; p.w = __expf(lg.w) / L.w;
    *reinterpret_cast<float4*>(&probs[(size_t)n * NCLS + c4]) = p;
}

extern "C" void kernel_launch(void* const* d_in, const int* in_sizes, int n_in,
                              void* d_out, int out_size, void* d_ws, size_t ws_size,
                              hipStream_t stream) {
    const float* H     = (const float*)d_in[0];
    const int*   batch = (const int*)d_in[1];
    // d_in[2] = num_segments (scalar) — constant 2048, unused
    const float* W1    = (const float*)d_in[3];
    const float* b1    = (const float*)d_in[4];
    const float* W2    = (const float*)d_in[5];
    const float* b2    = (const float*)d_in[6];

    float* out    = (float*)d_out;
    float* logits = out;                                   // [N, 128]
    float* probs  = out + (size_t)N_NODES * NCLS;          // [N, 128]

    char* ws = (char*)d_ws;
    short* W1t  = (short*)ws;                              // 256*256 bf16 = 128 KB
    short* W2t  = (short*)(ws + 131072);                   // 128*256 bf16 = 64 KB
    float* Lsum = (float*)(ws + 131072 + 65536);           // 2048*128 fp32 = 1 MB

    prep_kernel<<<256, 256, 0, stream>>>(W1, W2, W1t, W2t);
    zero_kernel<<<(NSEG * NCLS) / (4 * 256), 256, 0, stream>>>((float4*)Lsum);
    mlp_kernel<<<(N_NODES + 63) / 64, 256, 0, stream>>>(H, W1t, b1, W2t, b2, logits);
    seg_sum_kernel<<<(N_NODES + 255) / 256, 256, 0, stream>>>(logits, batch, Lsum);
    probs_kernel<<<(N_NODES * 32 + 255) / 256, 256, 0, stream>>>(logits, batch, Lsum, probs);
}